// Round 10
// baseline (254.418 us; speedup 1.0000x reference)
//
#include <hip/hip_runtime.h>

#define NL   4
#define NH   4
#define HD   64
#define CD   256
#define SQL  1024
#define BB   16

typedef _Float16 half8 __attribute__((ext_vector_type(8)));
typedef _Float16 half4 __attribute__((ext_vector_type(4)));
typedef _Float16 half2v __attribute__((ext_vector_type(2)));
typedef float    f32x4 __attribute__((ext_vector_type(4)));
typedef float    f32x16 __attribute__((ext_vector_type(16)));
typedef unsigned short u16x8 __attribute__((ext_vector_type(8)));
typedef unsigned int  uint4v __attribute__((ext_vector_type(4)));

static __device__ __forceinline__ float bf2f(unsigned short u) {
    union { unsigned int i; float f; } v; v.i = ((unsigned int)u) << 16; return v.f;
}
static __device__ __forceinline__ unsigned short f2bf(float f) {
    union { float f; unsigned int i; } v; v.f = f;
    unsigned int u = v.i;
    return (unsigned short)((u + 0x7fffu + ((u >> 16) & 1u)) >> 16);
}

// inline dtype detect: 1 = inputs are packed bf16, 0 = f32. 16 independent
// dwordx4 loads (R18 fix: was a serial dependent chain).
static __device__ __forceinline__ int detect_flag(const void* win) {
    const uint4v* w = (const uint4v*)win;
    int cnt = 0;
    uint4v u[16];
#pragma unroll
    for (int i = 0; i < 16; i++) u[i] = w[i];
#pragma unroll
    for (int i = 0; i < 16; i++)
#pragma unroll
        for (int j = 0; j < 4; j++) {
            unsigned int lo = u[i][j] & 0xFFFFu;
            int e = (int)((lo >> 7) & 0xFF);
            cnt += (e >= 96 && e <= 144) ? 1 : 0;
        }
    return cnt >= 48 ? 1 : 0;
}

// ---------- merged prep (unchanged) ----------
// x: (B,C,S)->(B,S,C) f16 row-major (gemm B-frags).
// kv: -> kaF / vtF in 32x32x16 MFMA-A-FRAGMENT ORDER: per (layer*NH+h),
//     per 64-l-tile, 8 chunks of [64 entries][8 halfs]. Each chunk is 1KB
//     with entry = lane*16B: a perfectly coalesced global_load_dwordx4.
//     ka chunk c=(lblk,kd16): entry(ln,hi) = K[lblk*32+ln][kd16*16+hi*8+j]
//     vt chunk c=(dblk,ks):   entry(ln,hi) = V[ks*16+hi*8+j][dblk*32+ln]
// w: elementwise cvt. Publishes dtype flag to *flagp.
__global__ __launch_bounds__(256) void prep_all(const void* __restrict__ xin,
                                                const void* __restrict__ win,
                                                const void* __restrict__ kvin,
                                                _Float16* __restrict__ x16,
                                                _Float16* __restrict__ w16,
                                                _Float16* __restrict__ kaF,
                                                _Float16* __restrict__ vtF,
                                                int* __restrict__ flagp) {
    __shared__ __align__(16) _Float16 tile[64][72];
    const int bi = blockIdx.x;
    const int t = threadIdx.x;
    const int isbf = detect_flag(win);

    if (bi < 1024) {
        // ---- prep_x: (B,C,S) -> (B,S,C) f16 ----
        const int st = bi & 15, ct = (bi >> 4) & 3, b = bi >> 6;
        const int r = t >> 2, seg = t & 3;
        const size_t base = ((size_t)(b * CD + ct * 64 + r)) * SQL + st * 64 + seg * 16;
        float v[16];
        if (isbf) {
            const unsigned short* src = (const unsigned short*)xin + base;
            u16x8 u0 = *(const u16x8*)(src);
            u16x8 u1 = *(const u16x8*)(src + 8);
#pragma unroll
            for (int j = 0; j < 8; j++) { v[j] = bf2f(u0[j]); v[8 + j] = bf2f(u1[j]); }
        } else {
            const float* src = (const float*)xin + base;
#pragma unroll
            for (int c = 0; c < 4; c++) {
                f32x4 a = *(const f32x4*)(src + c * 4);
#pragma unroll
                for (int j = 0; j < 4; j++) v[c * 4 + j] = a[j];
            }
        }
#pragma unroll
        for (int j = 0; j < 16; j++) tile[r][seg * 16 + j] = (_Float16)v[j];
        __syncthreads();
        half8 o0, o1;
#pragma unroll
        for (int j = 0; j < 8; j++) { o0[j] = tile[seg * 16 + j][r]; o1[j] = tile[seg * 16 + 8 + j][r]; }
        _Float16* dt = x16 + ((size_t)(b * SQL + st * 64 + r)) * CD + ct * 64 + seg * 16;
        *(half8*)(dt) = o0;
        *(half8*)(dt + 8) = o1;
    } else if (bi < 1280) {
        // ---- prep_kv -> 32x32-fragment-ordered kaF / vtF ----
        const int j2 = bi - 1024;
        const int lt = j2 & 15, ih = j2 >> 4;
        const int r = t >> 2, seg = t & 3;
        const size_t base = ((size_t)(ih * SQL + lt * 64 + r)) * HD + seg * 16;
        float v[16];
        if (isbf) {
            const unsigned short* src = (const unsigned short*)kvin + base;
            u16x8 u0 = *(const u16x8*)(src);
            u16x8 u1 = *(const u16x8*)(src + 8);
#pragma unroll
            for (int j = 0; j < 8; j++) { v[j] = bf2f(u0[j]); v[8 + j] = bf2f(u1[j]); }
        } else {
            const float* src = (const float*)kvin + base;
#pragma unroll
            for (int c = 0; c < 4; c++) {
                f32x4 a = *(const f32x4*)(src + c * 4);
#pragma unroll
                for (int j = 0; j < 4; j++) v[c * 4 + j] = a[j];
            }
        }
#pragma unroll
        for (int j = 0; j < 16; j++) tile[r][seg * 16 + j] = (_Float16)v[j];
        __syncthreads();
        // tile[l_local][d]. Emit 32x32x16 A-frags.
        const int l = t & 63, hie = l >> 5, lne = l & 31;
        _Float16* kaB = kaF + ((size_t)ih << 16);
        _Float16* vtB = vtF + ((size_t)ih << 16);
#pragma unroll
        for (int it = 0; it < 2; it++) {
            const int c = (t >> 6) + it * 4;       // 0..7
            half8 ok = *(const half8*)(&tile[(c >> 2) * 32 + lne][(c & 3) * 16 + hie * 8]);
            half8 ov;
#pragma unroll
            for (int j = 0; j < 8; j++)
                ov[j] = tile[(c & 3) * 16 + hie * 8 + j][(c >> 2) * 32 + lne];
            *(half8*)(kaB + ((lt * 8 + c) << 9) + l * 8) = ok;
            *(half8*)(vtB + ((lt * 8 + c) << 9) + l * 8) = ov;
        }
    } else {
        // ---- prep_w: elementwise cvt (+ flag publish) ----
        if (bi == 1280 && t == 0) *flagp = isbf;
        const int i = (bi - 1280) * 256 + t;
        const size_t base = (size_t)i * 8;
        half8 h;
        if (isbf) {
            u16x8 u = *(const u16x8*)((const unsigned short*)win + base);
#pragma unroll
            for (int j = 0; j < 8; j++) h[j] = (_Float16)bf2f(u[j]);
        } else {
            const float* p = (const float*)win + base;
            f32x4 a0 = *(const f32x4*)(p);
            f32x4 a1 = *(const f32x4*)(p + 4);
#pragma unroll
            for (int j = 0; j < 4; j++) { h[j] = (_Float16)a0[j]; h[4 + j] = (_Float16)a1[j]; }
        }
        *(half8*)(w16 + base) = h;
    }
}

// ---------- fused layer (R24: barrier-free streaming + l-split TLP) ----------
// R23 closed the books: MFMA busy 7.5us/SIMD (2 waves x 288 MFMA x 32cyc --
// a 32x32x16 occupies one SIMD's matrix pipe ~32 cyc), VALU 11.5us/SIMD
// (exp2-trans+pack+addr), K/V movement 2MB/CU through the ~64B/cyc vector
// return path ~13.7us. Wall 43.5 vs ~max-pipe 13.7: OVERLAP failure -- 2
// in-order waves/SIMD cannot keep 3 pipes busy. Every prior "add TLP" try
// was confounded (R15 traffic x2, R20 spills, R21 barriers+LDS generations).
// R24 is the clean test: wave (sg,hl) = s-group sg x l-half hl (8 tiles).
// Per-wave traffic halves, waves double -> per-CU traffic UNCHANGED, TLP
// 2->4 waves/SIMD, VGPR ~120 fits the 128 cap of (512,2) (CUDA-style min
// blocks/CU, confirmed R20/R21). No LDS/barriers in the loop; ONE barrier at
// the end: hl=1 publishes partial (O, sum-exp) to 38KB stride-37 scratch
// (R21-proven, refcheck-passed), hl=0 combines+stores. Softmax is linear
// pre-norm so partials add exactly. Cost: q-gemm duplicated (+11% MFMA).
__global__ __launch_bounds__(512, 2) void layer_fused(const _Float16* __restrict__ xg,
                                                      _Float16* __restrict__ xout,
                                                      const _Float16* __restrict__ w16,
                                                      const _Float16* __restrict__ kaF,
                                                      const _Float16* __restrict__ vtF,
                                                      const int* __restrict__ flagp,
                                                      void* __restrict__ outp,
                                                      int L) {
    __shared__ __align__(16) float scr[9472];   // (sg*64+lane)*37 + 0..32, max 9467
    const int sb = blockIdx.x;
    const int h  = blockIdx.y;
    const int b  = blockIdx.z;
    const int t  = threadIdx.x;
    const int wv = t >> 6, lane = t & 63, ln = lane & 31, hi = lane >> 5;
    const int sg = wv & 3, hl = wv >> 2;      // s-group, l-half
    const int s0 = sb * 128 + sg * 32;        // wave's 32 s-columns
    const int lt0 = hl * 8;                   // wave's 8 l-tiles

    const int isbf_final = (L == NL - 1) ? *flagp : 0;

    const _Float16* kaB = kaF + ((size_t)(L * NH + h) << 16) + lane * 8;
    const _Float16* vtB = vtF + ((size_t)(L * NH + h) << 16) + lane * 8;

    // ---- gemm: q^T[d=64][s=32], 32x32x16 (computed by both l-halves) ----
    f32x16 gacc[2];
#pragma unroll
    for (int dblk = 0; dblk < 2; dblk++)
#pragma unroll
        for (int r = 0; r < 16; r++) gacc[dblk][r] = 0.0f;
    const _Float16* wb = w16 + ((size_t)L << 16) + ((size_t)(h * 64) << 8);
#pragma unroll
    for (int kc = 0; kc < 16; kc++) {
        half8 bx = *(const half8*)(xg + ((size_t)((b << 10) + s0 + ln) << 8) + kc * 16 + hi * 8);
#pragma unroll
        for (int dblk = 0; dblk < 2; dblk++) {
            half8 aw = *(const half8*)(wb + ((size_t)(dblk * 32 + ln) << 8) + kc * 16 + hi * 8);
            gacc[dblk] = __builtin_amdgcn_mfma_f32_32x32x16_f16(aw, bx, gacc[dblk], 0, 0, 0);
        }
    }

    // q C-tile -> QK B-frags (scale 1/8*log2e folded), 8 permlane swaps
    const float sc = 0.180336880111120f;
    half8 qb[4];
#pragma unroll
    for (int dblk = 0; dblk < 2; dblk++)
#pragma unroll
        for (int k1 = 0; k1 < 2; k1++) {
            unsigned int u01 = __builtin_bit_cast(unsigned int,
                __builtin_amdgcn_cvt_pkrtz(gacc[dblk][k1 * 8 + 0] * sc, gacc[dblk][k1 * 8 + 1] * sc));
            unsigned int u23 = __builtin_bit_cast(unsigned int,
                __builtin_amdgcn_cvt_pkrtz(gacc[dblk][k1 * 8 + 2] * sc, gacc[dblk][k1 * 8 + 3] * sc));
            unsigned int w01 = __builtin_bit_cast(unsigned int,
                __builtin_amdgcn_cvt_pkrtz(gacc[dblk][k1 * 8 + 4] * sc, gacc[dblk][k1 * 8 + 5] * sc));
            unsigned int w23 = __builtin_bit_cast(unsigned int,
                __builtin_amdgcn_cvt_pkrtz(gacc[dblk][k1 * 8 + 6] * sc, gacc[dblk][k1 * 8 + 7] * sc));
            asm("v_permlane32_swap_b32 %0, %1" : "+v"(u01), "+v"(w01));
            asm("v_permlane32_swap_b32 %0, %1" : "+v"(u23), "+v"(w23));
            uint4v q; q[0] = u01; q[1] = u23; q[2] = w01; q[3] = w23;
            qb[dblk * 2 + k1] = __builtin_bit_cast(half8, q);
        }

    f32x16 oacc[2];
#pragma unroll
    for (int dblk = 0; dblk < 2; dblk++)
#pragma unroll
        for (int r = 0; r < 16; r++) oacc[dblk][r] = 0.0f;
    f32x4 rsum;
#pragma unroll
    for (int r = 0; r < 4; r++) rsum[r] = 0.0f;

    // per-tile compute: QK -> exp/pack/swap -> PV (R18 body, registers only)
    auto process = [&](const half8* ka, const half8* va) {
        f32x16 stt[2];
#pragma unroll
        for (int lblk = 0; lblk < 2; lblk++)
#pragma unroll
            for (int r = 0; r < 16; r++) stt[lblk][r] = 0.0f;
        __builtin_amdgcn_s_setprio(1);
#pragma unroll
        for (int lblk = 0; lblk < 2; lblk++)
#pragma unroll
            for (int kd = 0; kd < 4; kd++)
                stt[lblk] = __builtin_amdgcn_mfma_f32_32x32x16_f16(
                    ka[lblk * 4 + kd], qb[kd], stt[lblk], 0, 0, 0);
        __builtin_amdgcn_s_setprio(0);

        half8 pb[4];
#pragma unroll
        for (int lblk = 0; lblk < 2; lblk++) {
            float e[16];
#pragma unroll
            for (int r = 0; r < 16; r++) e[r] = __builtin_amdgcn_exp2f(stt[lblk][r]);
#pragma unroll
            for (int g = 0; g < 4; g++)
                rsum[g] += (e[g * 4 + 0] + e[g * 4 + 1]) + (e[g * 4 + 2] + e[g * 4 + 3]);
#pragma unroll
            for (int k1 = 0; k1 < 2; k1++) {
                unsigned int u01 = __builtin_bit_cast(unsigned int,
                    __builtin_amdgcn_cvt_pkrtz(e[k1 * 8 + 0], e[k1 * 8 + 1]));
                unsigned int u23 = __builtin_bit_cast(unsigned int,
                    __builtin_amdgcn_cvt_pkrtz(e[k1 * 8 + 2], e[k1 * 8 + 3]));
                unsigned int w01 = __builtin_bit_cast(unsigned int,
                    __builtin_amdgcn_cvt_pkrtz(e[k1 * 8 + 4], e[k1 * 8 + 5]));
                unsigned int w23 = __builtin_bit_cast(unsigned int,
                    __builtin_amdgcn_cvt_pkrtz(e[k1 * 8 + 6], e[k1 * 8 + 7]));
                asm("v_permlane32_swap_b32 %0, %1" : "+v"(u01), "+v"(w01));
                asm("v_permlane32_swap_b32 %0, %1" : "+v"(u23), "+v"(w23));
                uint4v p; p[0] = u01; p[1] = u23; p[2] = w01; p[3] = w23;
                pb[lblk * 2 + k1] = __builtin_bit_cast(half8, p);
            }
        }

        __builtin_amdgcn_s_setprio(1);
#pragma unroll
        for (int dblk = 0; dblk < 2; dblk++)
#pragma unroll
            for (int ks = 0; ks < 4; ks++)
                oacc[dblk] = __builtin_amdgcn_mfma_f32_32x32x16_f16(
                    va[dblk * 4 + ks], pb[ks], oacc[dblk], 0, 0, 0);
        __builtin_amdgcn_s_setprio(0);
    };

#define LOADK(dst, lt)                                                        \
    do {                                                                      \
        _Pragma("unroll")                                                     \
        for (int c = 0; c < 8; c++)                                           \
            dst[c] = *(const half8*)(kaB + (((lt) * 8 + c) << 9));            \
    } while (0)
#define LOADV(dst, lt)                                                        \
    do {                                                                      \
        _Pragma("unroll")                                                     \
        for (int c = 0; c < 8; c++)                                           \
            dst[c] = *(const half8*)(vtB + (((lt) * 8 + c) << 9));            \
    } while (0)

    half8 ka0[8], ka1[8], va[8];
    LOADK(ka0, lt0);
    LOADV(va, lt0);               // iteration 0's V latency pre-covered

#pragma unroll 1
    for (int i = 0; i < 8; i += 2) {
        LOADK(ka1, lt0 + i + 1);  // K(t+1): covered by all of tile t
        process(ka0, va);
        LOADV(va, lt0 + i + 1);   // V(t+1): used only after QK+exp of t+1
        if (i + 2 < 8) LOADK(ka0, lt0 + i + 2);
        process(ka1, va);
        if (i + 2 < 8) LOADV(va, lt0 + i + 2);
    }
#undef LOADK
#undef LOADV

    // ---- combine l-halves via LDS scratch; single barrier in the kernel ----
    float rs = (rsum[0] + rsum[1]) + (rsum[2] + rsum[3]);
    const int sidx = (sg * 64 + lane) * 37;   // stride 37: coprime w/ 32 banks

    if (hl == 1) {
#pragma unroll
        for (int dblk = 0; dblk < 2; dblk++)
#pragma unroll
            for (int r = 0; r < 16; r++) scr[sidx + dblk * 16 + r] = oacc[dblk][r];
        scr[sidx + 32] = rs;
    }
    __syncthreads();

    if (hl == 0) {
#pragma unroll
        for (int dblk = 0; dblk < 2; dblk++)
#pragma unroll
            for (int r = 0; r < 16; r++) oacc[dblk][r] += scr[sidx + dblk * 16 + r];
        rs += scr[sidx + 32];

        // denominator: pair-combine own+partner (lane<->lane+32, hi halves)
        unsigned int ra = __builtin_bit_cast(unsigned int, rs);
        unsigned int rb = ra;
        asm("" : "+v"(rb));   // force distinct register lineage
        asm("v_permlane32_swap_b32 %0, %1" : "+v"(ra), "+v"(rb));
        const float inv = 1.0f / (__builtin_bit_cast(float, ra) + __builtin_bit_cast(float, rb));
        const int s = s0 + ln;

        if (L < NL - 1) {
#pragma unroll
            for (int dblk = 0; dblk < 2; dblk++)
#pragma unroll
                for (int q2 = 0; q2 < 4; q2++) {
                    half4 hv;
#pragma unroll
                    for (int r = 0; r < 4; r++) hv[r] = (_Float16)(oacc[dblk][q2 * 4 + r] * inv);
                    *(half4*)(xout + (((size_t)((b << 10) + s)) << 8) +
                              (h << 6) + dblk * 32 + q2 * 8 + hi * 4) = hv;
                }
        } else if (isbf_final) {
#pragma unroll
            for (int dblk = 0; dblk < 2; dblk++)
#pragma unroll
                for (int q2 = 0; q2 < 4; q2++)
#pragma unroll
                    for (int r = 0; r < 4; r++) {
                        const int c = (h << 6) + dblk * 32 + q2 * 8 + hi * 4 + r;
                        ((unsigned short*)outp)[(((size_t)(b * CD + c)) << 10) + s] =
                            f2bf(oacc[dblk][q2 * 4 + r] * inv);
                    }
        } else {
#pragma unroll
            for (int dblk = 0; dblk < 2; dblk++)
#pragma unroll
                for (int q2 = 0; q2 < 4; q2++)
#pragma unroll
                    for (int r = 0; r < 4; r++) {
                        const int c = (h << 6) + dblk * 32 + q2 * 8 + hi * 4 + r;
                        ((float*)outp)[(((size_t)(b * CD + c)) << 10) + s] =
                            oacc[dblk][q2 * 4 + r] * inv;
                    }
        }
    }
}

extern "C" void kernel_launch(void* const* d_in, const int* in_sizes, int n_in,
                              void* d_out, int out_size, void* d_ws, size_t ws_size,
                              hipStream_t stream) {
    const void* xin = d_in[0];
    // d_in[1] = length: used only for its shape (L=1024) — values irrelevant
    const void* win = d_in[2];
    const void* kvin = d_in[3];

    char* ws = (char*)d_ws;
    const size_t MB = 1u << 20;
    _Float16* xa  = (_Float16*)(ws);               // 8 MB  (B,S,C) f16
    _Float16* xb  = (_Float16*)(ws + 8 * MB);      // 8 MB  ping-pong
    _Float16* w16 = (_Float16*)(ws + 16 * MB);     // 0.5 MB
    _Float16* kaF = (_Float16*)(ws + 17 * MB);     // 2 MB  K fragment-order
    _Float16* vtF = (_Float16*)(ws + 19 * MB);     // 2 MB  V^T fragment-order
    int*      flg = (int*)(ws + 21 * MB);          // dtype flag

    prep_all<<<dim3(1024 + 256 + 128), 256, 0, stream>>>(xin, win, kvin, xa, w16, kaF, vtF, flg);

    _Float16* cur = xa;
    _Float16* nxt = xb;
    for (int i = 0; i < NL; i++) {
        layer_fused<<<dim3(SQL / 128, NH, BB), 512, 0, stream>>>(cur, nxt, w16, kaF, vtF,
                                                                 flg, d_out, i);
        _Float16* tmp = cur; cur = nxt; nxt = tmp;
    }
}

// Round 11
// 200.025 us; speedup vs baseline: 1.2719x; 1.2719x over previous
//
#include <hip/hip_runtime.h>

#define NL   4
#define NH   4
#define HD   64
#define CD   256
#define SQL  1024
#define BB   16

typedef _Float16 half8 __attribute__((ext_vector_type(8)));
typedef _Float16 half4 __attribute__((ext_vector_type(4)));
typedef _Float16 half2v __attribute__((ext_vector_type(2)));
typedef float    f32x4 __attribute__((ext_vector_type(4)));
typedef float    f32x16 __attribute__((ext_vector_type(16)));
typedef unsigned short u16x8 __attribute__((ext_vector_type(8)));
typedef unsigned int  uint4v __attribute__((ext_vector_type(4)));

static __device__ __forceinline__ float bf2f(unsigned short u) {
    union { unsigned int i; float f; } v; v.i = ((unsigned int)u) << 16; return v.f;
}
static __device__ __forceinline__ unsigned short f2bf(float f) {
    union { float f; unsigned int i; } v; v.f = f;
    unsigned int u = v.i;
    return (unsigned short)((u + 0x7fffu + ((u >> 16) & 1u)) >> 16);
}

// inline dtype detect: 1 = inputs are packed bf16, 0 = f32. 16 independent
// dwordx4 loads (R18 fix: was a serial dependent chain).
static __device__ __forceinline__ int detect_flag(const void* win) {
    const uint4v* w = (const uint4v*)win;
    int cnt = 0;
    uint4v u[16];
#pragma unroll
    for (int i = 0; i < 16; i++) u[i] = w[i];
#pragma unroll
    for (int i = 0; i < 16; i++)
#pragma unroll
        for (int j = 0; j < 4; j++) {
            unsigned int lo = u[i][j] & 0xFFFFu;
            int e = (int)((lo >> 7) & 0xFF);
            cnt += (e >= 96 && e <= 144) ? 1 : 0;
        }
    return cnt >= 48 ? 1 : 0;
}

// ---------- merged prep ----------
// x: (B,C,S)->(B,S,C) f16 row-major (gemm B-frags).
// kv: -> kaF / vtF in 32x32x16 MFMA-A-FRAGMENT ORDER: per (layer*NH+h),
//     per 64-l-tile, 8 chunks of [64 entries][8 halfs], glds-compatible.
//     ka chunk c=(lblk,kd16): entry(ln,hi) = K[lblk*32+ln][kd16*16+hi*8+j]
//     vt chunk c=(dblk,ks):   entry(ln,hi) = V[ks*16+hi*8+j][dblk*32+ln]
// w: elementwise cvt. Publishes dtype flag to *flagp.
__global__ __launch_bounds__(256) void prep_all(const void* __restrict__ xin,
                                                const void* __restrict__ win,
                                                const void* __restrict__ kvin,
                                                _Float16* __restrict__ x16,
                                                _Float16* __restrict__ w16,
                                                _Float16* __restrict__ kaF,
                                                _Float16* __restrict__ vtF,
                                                int* __restrict__ flagp) {
    __shared__ __align__(16) _Float16 tile[64][72];
    const int bi = blockIdx.x;
    const int t = threadIdx.x;
    const int isbf = detect_flag(win);

    if (bi < 1024) {
        // ---- prep_x: (B,C,S) -> (B,S,C) f16 ----
        const int st = bi & 15, ct = (bi >> 4) & 3, b = bi >> 6;
        const int r = t >> 2, seg = t & 3;
        const size_t base = ((size_t)(b * CD + ct * 64 + r)) * SQL + st * 64 + seg * 16;
        float v[16];
        if (isbf) {
            const unsigned short* src = (const unsigned short*)xin + base;
            u16x8 u0 = *(const u16x8*)(src);
            u16x8 u1 = *(const u16x8*)(src + 8);
#pragma unroll
            for (int j = 0; j < 8; j++) { v[j] = bf2f(u0[j]); v[8 + j] = bf2f(u1[j]); }
        } else {
            const float* src = (const float*)xin + base;
#pragma unroll
            for (int c = 0; c < 4; c++) {
                f32x4 a = *(const f32x4*)(src + c * 4);
#pragma unroll
                for (int j = 0; j < 4; j++) v[c * 4 + j] = a[j];
            }
        }
#pragma unroll
        for (int j = 0; j < 16; j++) tile[r][seg * 16 + j] = (_Float16)v[j];
        __syncthreads();
        half8 o0, o1;
#pragma unroll
        for (int j = 0; j < 8; j++) { o0[j] = tile[seg * 16 + j][r]; o1[j] = tile[seg * 16 + 8 + j][r]; }
        _Float16* dt = x16 + ((size_t)(b * SQL + st * 64 + r)) * CD + ct * 64 + seg * 16;
        *(half8*)(dt) = o0;
        *(half8*)(dt + 8) = o1;
    } else if (bi < 1280) {
        // ---- prep_kv -> 32x32-fragment-ordered kaF / vtF ----
        const int j2 = bi - 1024;
        const int lt = j2 & 15, ih = j2 >> 4;
        const int r = t >> 2, seg = t & 3;
        const size_t base = ((size_t)(ih * SQL + lt * 64 + r)) * HD + seg * 16;
        float v[16];
        if (isbf) {
            const unsigned short* src = (const unsigned short*)kvin + base;
            u16x8 u0 = *(const u16x8*)(src);
            u16x8 u1 = *(const u16x8*)(src + 8);
#pragma unroll
            for (int j = 0; j < 8; j++) { v[j] = bf2f(u0[j]); v[8 + j] = bf2f(u1[j]); }
        } else {
            const float* src = (const float*)kvin + base;
#pragma unroll
            for (int c = 0; c < 4; c++) {
                f32x4 a = *(const f32x4*)(src + c * 4);
#pragma unroll
                for (int j = 0; j < 4; j++) v[c * 4 + j] = a[j];
            }
        }
#pragma unroll
        for (int j = 0; j < 16; j++) tile[r][seg * 16 + j] = (_Float16)v[j];
        __syncthreads();
        // tile[l_local][d]. Emit 32x32x16 A-frags.
        const int l = t & 63, hie = l >> 5, lne = l & 31;
        _Float16* kaB = kaF + ((size_t)ih << 16);
        _Float16* vtB = vtF + ((size_t)ih << 16);
#pragma unroll
        for (int it = 0; it < 2; it++) {
            const int c = (t >> 6) + it * 4;       // 0..7
            half8 ok = *(const half8*)(&tile[(c >> 2) * 32 + lne][(c & 3) * 16 + hie * 8]);
            half8 ov;
#pragma unroll
            for (int j = 0; j < 8; j++)
                ov[j] = tile[(c & 3) * 16 + hie * 8 + j][(c >> 2) * 32 + lne];
            *(half8*)(kaB + ((lt * 8 + c) << 9) + l * 8) = ok;
            *(half8*)(vtB + ((lt * 8 + c) << 9) + l * 8) = ov;
        }
    } else {
        // ---- prep_w: elementwise cvt (+ flag publish) ----
        if (bi == 1280 && t == 0) *flagp = isbf;
        const int i = (bi - 1280) * 256 + t;
        const size_t base = (size_t)i * 8;
        half8 h;
        if (isbf) {
            u16x8 u = *(const u16x8*)((const unsigned short*)win + base);
#pragma unroll
            for (int j = 0; j < 8; j++) h[j] = (_Float16)bf2f(u[j]);
        } else {
            const float* p = (const float*)win + base;
            f32x4 a0 = *(const f32x4*)(p);
            f32x4 a1 = *(const f32x4*)(p + 4);
#pragma unroll
            for (int j = 0; j < 4; j++) { h[j] = (_Float16)a0[j]; h[4 + j] = (_Float16)a1[j]; }
        }
        *(half8*)(w16 + base) = h;
    }
}

// ---------- fused layer (R25 = revert to R18, the session optimum) ----------
// Seven structural experiments since R18 (counted-vmcnt R16, s-split R15,
// spill-fix l-split R20/R21, cooperative merge R19, barrier-free streaming
// R23, streaming+TLP R24) all landed neutral-to-worse. Falsified: barrier
// drain, LDS bandwidth, spills, TLP (clean test R24: 2x waves, same traffic,
// no barriers -> SLOWER). Confirmed once: work reduction pays ~1:1 (R17).
// R18's config is the measured optimum: 201.4 us total, 38 us/layer,
// absmax 3.05e-5. This round restores it exactly.
// Structure: 256 thr (4 waves x 32 s-cols), dbuf 2x32KB LDS staged via
// global_load_lds (16 chunks/tile-pair, 4/wave), 8 regions of 128 l with one
// __syncthreads each; per region the two 64-l sub-tiles A/B are processed
// with phases interleaved (QK_A -> vabA -> QK_B -> exp_A -> vabB -> PV_A ->
// exp_B -> PV_B; per-wave parity decorrelates); all MFMA 32x32x16 full-rate;
// q C-tile and exp(S^T) convert to B-frags in-register via cvt_pkrtz +
// v_permlane32_swap_b32; row-sum on VALU; exp2 with log2e folded in q scale.
__global__ __launch_bounds__(256, 2) void layer_fused(const _Float16* __restrict__ xg,
                                                      _Float16* __restrict__ xout,
                                                      const _Float16* __restrict__ w16,
                                                      const _Float16* __restrict__ kaF,
                                                      const _Float16* __restrict__ vtF,
                                                      const int* __restrict__ flagp,
                                                      void* __restrict__ outp,
                                                      int L) {
    __shared__ __align__(16) _Float16 kvbuf[2][16384];  // [buf][2 sub x 16 chunks x 512]
    const int sb = blockIdx.x;
    const int h  = blockIdx.y;
    const int b  = blockIdx.z;
    const int t  = threadIdx.x;
    const int wv = t >> 6, lane = t & 63, ln = lane & 31, hi = lane >> 5;
    const int s0 = sb * 128 + wv * 32;        // wave's 32 s-columns
    const int par = (sb ^ h ^ b ^ wv) & 1;    // region sub-tile order A/B

    const int isbf_final = (L == NL - 1) ? *flagp : 0;

    const _Float16* kaB = kaF + ((size_t)(L * NH + h) << 16);
    const _Float16* vtB = vtF + ((size_t)(L * NH + h) << 16);

    // stage 64-l-tile lt into kvbuf[buf] half hf: wave wv stages 4 of 16 chunks.
    auto stage = [&](int lt, int buf, int hf) {
#pragma unroll
        for (int j = 0; j < 4; j++) {
            const int c = wv * 4 + j;
            const _Float16* src = (c < 8)
                ? kaB + (((lt * 8 + c) << 9))
                : vtB + (((lt * 8 + (c - 8)) << 9));
            __builtin_amdgcn_global_load_lds(
                (const __attribute__((address_space(1))) void*)(src + lane * 8),
                (__attribute__((address_space(3))) void*)(&kvbuf[buf][hf * 8192 + c * 512]),
                16, 0, 0);
        }
    };

    stage(0, 0, 0);
    stage(1, 0, 1);   // overlap the gemm below

    // ---- gemm: q^T[d=64][s=32], 32x32x16, M=d 2x32, N=s=32, K=c 16x16 ----
    f32x16 gacc[2];
#pragma unroll
    for (int dblk = 0; dblk < 2; dblk++)
#pragma unroll
        for (int r = 0; r < 16; r++) gacc[dblk][r] = 0.0f;
    const _Float16* wb = w16 + ((size_t)L << 16) + ((size_t)(h * 64) << 8);
#pragma unroll
    for (int kc = 0; kc < 16; kc++) {
        half8 bx = *(const half8*)(xg + ((size_t)((b << 10) + s0 + ln) << 8) + kc * 16 + hi * 8);
#pragma unroll
        for (int dblk = 0; dblk < 2; dblk++) {
            half8 aw = *(const half8*)(wb + ((size_t)(dblk * 32 + ln) << 8) + kc * 16 + hi * 8);
            gacc[dblk] = __builtin_amdgcn_mfma_f32_32x32x16_f16(aw, bx, gacc[dblk], 0, 0, 0);
        }
    }

    // q C-tile -> QK B-frags (scale 1/8*log2e folded), 8 permlane swaps
    const float sc = 0.180336880111120f;
    half8 qb[4];
#pragma unroll
    for (int dblk = 0; dblk < 2; dblk++)
#pragma unroll
        for (int k1 = 0; k1 < 2; k1++) {
            unsigned int u01 = __builtin_bit_cast(unsigned int,
                __builtin_amdgcn_cvt_pkrtz(gacc[dblk][k1 * 8 + 0] * sc, gacc[dblk][k1 * 8 + 1] * sc));
            unsigned int u23 = __builtin_bit_cast(unsigned int,
                __builtin_amdgcn_cvt_pkrtz(gacc[dblk][k1 * 8 + 2] * sc, gacc[dblk][k1 * 8 + 3] * sc));
            unsigned int w01 = __builtin_bit_cast(unsigned int,
                __builtin_amdgcn_cvt_pkrtz(gacc[dblk][k1 * 8 + 4] * sc, gacc[dblk][k1 * 8 + 5] * sc));
            unsigned int w23 = __builtin_bit_cast(unsigned int,
                __builtin_amdgcn_cvt_pkrtz(gacc[dblk][k1 * 8 + 6] * sc, gacc[dblk][k1 * 8 + 7] * sc));
            asm("v_permlane32_swap_b32 %0, %1" : "+v"(u01), "+v"(w01));
            asm("v_permlane32_swap_b32 %0, %1" : "+v"(u23), "+v"(w23));
            uint4v q; q[0] = u01; q[1] = u23; q[2] = w01; q[3] = w23;
            qb[dblk * 2 + k1] = __builtin_bit_cast(half8, q);
        }

    f32x16 oacc[2];
#pragma unroll
    for (int dblk = 0; dblk < 2; dblk++)
#pragma unroll
        for (int r = 0; r < 16; r++) oacc[dblk][r] = 0.0f;
    f32x4 rsum;
#pragma unroll
    for (int r = 0; r < 4; r++) rsum[r] = 0.0f;

    __syncthreads();   // tiles 0,1 staged

#pragma unroll 1
    for (int ltp = 0; ltp < 8; ltp++) {
        const int buf = ltp & 1;
        if (ltp < 7) {
            stage(2 * ltp + 2, buf ^ 1, 0);
            stage(2 * ltp + 3, buf ^ 1, 1);
        }

        const _Float16* baseA = &kvbuf[buf][par * 8192];
        const _Float16* baseB = &kvbuf[buf][(par ^ 1) * 8192];

        // K A-frags for BOTH subs up front (issued under matrix-pipe time)
        half8 kabA[8], kabB[8];
#pragma unroll
        for (int c = 0; c < 8; c++) kabA[c] = *(const half8*)(baseA + c * 512 + lane * 8);
#pragma unroll
        for (int c = 0; c < 8; c++) kabB[c] = *(const half8*)(baseB + c * 512 + lane * 8);

        f32x16 sttA[2], sttB[2];
#pragma unroll
        for (int lblk = 0; lblk < 2; lblk++)
#pragma unroll
            for (int r = 0; r < 16; r++) { sttA[lblk][r] = 0.0f; sttB[lblk][r] = 0.0f; }

        // QK_A
        __builtin_amdgcn_s_setprio(1);
#pragma unroll
        for (int lblk = 0; lblk < 2; lblk++)
#pragma unroll
            for (int kd = 0; kd < 4; kd++)
                sttA[lblk] = __builtin_amdgcn_mfma_f32_32x32x16_f16(
                    kabA[lblk * 4 + kd], qb[kd], sttA[lblk], 0, 0, 0);
        __builtin_amdgcn_s_setprio(0);

        half8 vabA[8];
#pragma unroll
        for (int c = 0; c < 8; c++) vabA[c] = *(const half8*)(baseA + (8 + c) * 512 + lane * 8);

        // QK_B (independent of exp_A below: scheduler/pipe overlap)
        __builtin_amdgcn_s_setprio(1);
#pragma unroll
        for (int lblk = 0; lblk < 2; lblk++)
#pragma unroll
            for (int kd = 0; kd < 4; kd++)
                sttB[lblk] = __builtin_amdgcn_mfma_f32_32x32x16_f16(
                    kabB[lblk * 4 + kd], qb[kd], sttB[lblk], 0, 0, 0);
        __builtin_amdgcn_s_setprio(0);

        // exp_A -> pbA (VALU runs while QK_B drains the matrix pipe)
        half8 pbA[4];
#pragma unroll
        for (int lblk = 0; lblk < 2; lblk++) {
            float e[16];
#pragma unroll
            for (int r = 0; r < 16; r++) e[r] = __builtin_amdgcn_exp2f(sttA[lblk][r]);
#pragma unroll
            for (int g = 0; g < 4; g++)
                rsum[g] += (e[g * 4 + 0] + e[g * 4 + 1]) + (e[g * 4 + 2] + e[g * 4 + 3]);
#pragma unroll
            for (int k1 = 0; k1 < 2; k1++) {
                unsigned int u01 = __builtin_bit_cast(unsigned int,
                    __builtin_amdgcn_cvt_pkrtz(e[k1 * 8 + 0], e[k1 * 8 + 1]));
                unsigned int u23 = __builtin_bit_cast(unsigned int,
                    __builtin_amdgcn_cvt_pkrtz(e[k1 * 8 + 2], e[k1 * 8 + 3]));
                unsigned int w01 = __builtin_bit_cast(unsigned int,
                    __builtin_amdgcn_cvt_pkrtz(e[k1 * 8 + 4], e[k1 * 8 + 5]));
                unsigned int w23 = __builtin_bit_cast(unsigned int,
                    __builtin_amdgcn_cvt_pkrtz(e[k1 * 8 + 6], e[k1 * 8 + 7]));
                asm("v_permlane32_swap_b32 %0, %1" : "+v"(u01), "+v"(w01));
                asm("v_permlane32_swap_b32 %0, %1" : "+v"(u23), "+v"(w23));
                uint4v p; p[0] = u01; p[1] = u23; p[2] = w01; p[3] = w23;
                pbA[lblk * 2 + k1] = __builtin_bit_cast(half8, p);
            }
        }

        half8 vabB[8];
#pragma unroll
        for (int c = 0; c < 8; c++) vabB[c] = *(const half8*)(baseB + (8 + c) * 512 + lane * 8);

        // PV_A
        __builtin_amdgcn_s_setprio(1);
#pragma unroll
        for (int dblk = 0; dblk < 2; dblk++)
#pragma unroll
            for (int ks = 0; ks < 4; ks++)
                oacc[dblk] = __builtin_amdgcn_mfma_f32_32x32x16_f16(
                    vabA[dblk * 4 + ks], pbA[ks], oacc[dblk], 0, 0, 0);
        __builtin_amdgcn_s_setprio(0);

        // exp_B -> pbB (VALU under PV_A's matrix time)
        half8 pbB[4];
#pragma unroll
        for (int lblk = 0; lblk < 2; lblk++) {
            float e[16];
#pragma unroll
            for (int r = 0; r < 16; r++) e[r] = __builtin_amdgcn_exp2f(sttB[lblk][r]);
#pragma unroll
            for (int g = 0; g < 4; g++)
                rsum[g] += (e[g * 4 + 0] + e[g * 4 + 1]) + (e[g * 4 + 2] + e[g * 4 + 3]);
#pragma unroll
            for (int k1 = 0; k1 < 2; k1++) {
                unsigned int u01 = __builtin_bit_cast(unsigned int,
                    __builtin_amdgcn_cvt_pkrtz(e[k1 * 8 + 0], e[k1 * 8 + 1]));
                unsigned int u23 = __builtin_bit_cast(unsigned int,
                    __builtin_amdgcn_cvt_pkrtz(e[k1 * 8 + 2], e[k1 * 8 + 3]));
                unsigned int w01 = __builtin_bit_cast(unsigned int,
                    __builtin_amdgcn_cvt_pkrtz(e[k1 * 8 + 4], e[k1 * 8 + 5]));
                unsigned int w23 = __builtin_bit_cast(unsigned int,
                    __builtin_amdgcn_cvt_pkrtz(e[k1 * 8 + 6], e[k1 * 8 + 7]));
                asm("v_permlane32_swap_b32 %0, %1" : "+v"(u01), "+v"(w01));
                asm("v_permlane32_swap_b32 %0, %1" : "+v"(u23), "+v"(w23));
                uint4v p; p[0] = u01; p[1] = u23; p[2] = w01; p[3] = w23;
                pbB[lblk * 2 + k1] = __builtin_bit_cast(half8, p);
            }
        }

        // PV_B
        __builtin_amdgcn_s_setprio(1);
#pragma unroll
        for (int dblk = 0; dblk < 2; dblk++)
#pragma unroll
            for (int ks = 0; ks < 4; ks++)
                oacc[dblk] = __builtin_amdgcn_mfma_f32_32x32x16_f16(
                    vabB[dblk * 4 + ks], pbB[ks], oacc[dblk], 0, 0, 0);
        __builtin_amdgcn_s_setprio(0);

        __syncthreads();   // drains next-tile glds; protects buf reuse
    }

    // ---- denominator: pair-combine own+partner (lane<->lane+32) ----
    float rs = (rsum[0] + rsum[1]) + (rsum[2] + rsum[3]);
    unsigned int ra = __builtin_bit_cast(unsigned int, rs);
    unsigned int rb = ra;
    asm("" : "+v"(rb));   // force distinct register lineage
    asm("v_permlane32_swap_b32 %0, %1" : "+v"(ra), "+v"(rb));
    const float inv = 1.0f / (__builtin_bit_cast(float, ra) + __builtin_bit_cast(float, rb));
    const int s = s0 + ln;

    if (L < NL - 1) {
#pragma unroll
        for (int dblk = 0; dblk < 2; dblk++)
#pragma unroll
            for (int q2 = 0; q2 < 4; q2++) {
                half4 hv;
#pragma unroll
                for (int r = 0; r < 4; r++) hv[r] = (_Float16)(oacc[dblk][q2 * 4 + r] * inv);
                *(half4*)(xout + (((size_t)((b << 10) + s)) << 8) +
                          (h << 6) + dblk * 32 + q2 * 8 + hi * 4) = hv;
            }
    } else if (isbf_final) {
#pragma unroll
        for (int dblk = 0; dblk < 2; dblk++)
#pragma unroll
            for (int q2 = 0; q2 < 4; q2++)
#pragma unroll
                for (int r = 0; r < 4; r++) {
                    const int c = (h << 6) + dblk * 32 + q2 * 8 + hi * 4 + r;
                    ((unsigned short*)outp)[(((size_t)(b * CD + c)) << 10) + s] =
                        f2bf(oacc[dblk][q2 * 4 + r] * inv);
                }
    } else {
#pragma unroll
        for (int dblk = 0; dblk < 2; dblk++)
#pragma unroll
            for (int q2 = 0; q2 < 4; q2++)
#pragma unroll
                for (int r = 0; r < 4; r++) {
                    const int c = (h << 6) + dblk * 32 + q2 * 8 + hi * 4 + r;
                    ((float*)outp)[(((size_t)(b * CD + c)) << 10) + s] =
                        oacc[dblk][q2 * 4 + r] * inv;
                }
    }
}

extern "C" void kernel_launch(void* const* d_in, const int* in_sizes, int n_in,
                              void* d_out, int out_size, void* d_ws, size_t ws_size,
                              hipStream_t stream) {
    const void* xin = d_in[0];
    // d_in[1] = length: used only for its shape (L=1024) — values irrelevant
    const void* win = d_in[2];
    const void* kvin = d_in[3];

    char* ws = (char*)d_ws;
    const size_t MB = 1u << 20;
    _Float16* xa  = (_Float16*)(ws);               // 8 MB  (B,S,C) f16
    _Float16* xb  = (_Float16*)(ws + 8 * MB);      // 8 MB  ping-pong
    _Float16* w16 = (_Float16*)(ws + 16 * MB);     // 0.5 MB
    _Float16* kaF = (_Float16*)(ws + 17 * MB);     // 2 MB  K fragment-order
    _Float16* vtF = (_Float16*)(ws + 19 * MB);     // 2 MB  V^T fragment-order
    int*      flg = (int*)(ws + 21 * MB);          // dtype flag

    prep_all<<<dim3(1024 + 256 + 128), 256, 0, stream>>>(xin, win, kvin, xa, w16, kaF, vtF, flg);

    _Float16* cur = xa;
    _Float16* nxt = xb;
    for (int i = 0; i < NL; i++) {
        layer_fused<<<dim3(SQL / 128, NH, BB), 256, 0, stream>>>(cur, nxt, w16, kaF, vtF,
                                                                 flg, d_out, i);
        _Float16* tmp = cur; cur = nxt; nxt = tmp;
    }
}